// Round 7
// baseline (175.579 us; speedup 1.0000x reference)
//
#include <hip/hip_runtime.h>

// MACE body-3, round 7: 4-stage grid-parallel pipeline (launches are free).
//  K1 prep_misc : pack U3(+U2 tail) -> f16 B-frags (258KB, L2-resident)
//                 + wcomb[l] = w_fc2[l] @ w_lin[l]  (fuses last two linears)
//  K2 lin_k     : xv = so3_linear(irreps, w_fc1, b_fc1)       -> d_out (temp)
//  K3 mace_core : per atom: s3 regs -> 84x MFMA 32x32x16 f16 GEMM -> out1
//                 1 atom/block, 6 waves (mt x ng), 1024 blocks = 4 blocks/CU
//  K4 lin_k     : out = so3_linear(o1, wcomb, b_fc2)          -> d_out

typedef __attribute__((ext_vector_type(8)))  _Float16 f16x8;
typedef __attribute__((ext_vector_type(16))) float    f32x16;
typedef __attribute__((ext_vector_type(4)))  float    f32x4;

// ---- K1: U3/U2 fragment pack (blocks 0..62) + wcomb (blocks 63..65) ----
// frag idx = (ks*3 + nt)*64 + lane ; col oa = nt*32+(l&31),
// k-elems = 8 f16 at k = ks*16 + (l>>5)*8 + j.  84 k-steps (81 U3 + 3 U2).
__global__ void prep_misc(const float* __restrict__ U3, const float* __restrict__ U2,
                          const float* __restrict__ w_lin, const float* __restrict__ w_fc2,
                          _Float16* __restrict__ U3w, float* __restrict__ wcomb)
{
    if (blockIdx.x < 63) {
        int idx = blockIdx.x * 256 + threadIdx.x;   // 63*256 = 16128 exactly
        int ks = idx / 192, r = idx % 192;
        int nt = r >> 6, l = r & 63;
        int oa = nt * 32 + (l & 31), half = l >> 5;
        f16x8 v;
        if (ks < 81) {
            int b = ks / 9, ksub = ks % 9, ip0 = ksub * 16 + half * 8;
            #pragma unroll
            for (int j = 0; j < 8; ++j) {
                float f = (oa < 81) ? U3[(oa * 9 + b) * 144 + ip0 + j] : 0.f;
                v[j] = (_Float16)f;
            }
        } else {
            int ip0 = (ks - 81) * 16 + half * 8;
            #pragma unroll
            for (int j = 0; j < 8; ++j) {
                int ip2 = ip0 + j;
                float f = (oa < 81 && ip2 < 36) ? U2[oa * 36 + ip2] : 0.f;
                v[j] = (_Float16)f;
            }
        }
        ((f16x8*)U3w)[idx] = v;
    } else {
        // wcomb[l][e][c] = sum_d w_fc2[l][e][d] * w_lin[l][d][c]
        int l = blockIdx.x - 63;
        const float* wf = w_fc2 + l * 4096;
        const float* wl = w_lin + l * 4096;
        for (int i = threadIdx.x; i < 4096; i += 256) {
            int e = i >> 6, c = i & 63;
            float s = 0.f;
            #pragma unroll 8
            for (int d = 0; d < 64; ++d) s += wf[e * 64 + d] * wl[d * 64 + c];
            wcomb[l * 4096 + i] = s;
        }
    }
}

// ---- K2/K4: per-l 64x64 so3_linear, fp32 VALU, 4 rows/block ----
__global__ __launch_bounds__(256) void lin_k(const float* __restrict__ x,
                                             const float* __restrict__ w,
                                             const float* __restrict__ bias,
                                             float* __restrict__ y)
{
    __shared__ float xr[256];
    const int nm0 = blockIdx.x * 4;
    const int t = threadIdx.x;
    xr[t] = x[nm0 * 64 + t];
    __syncthreads();
    const int r = t >> 6, d = t & 63;
    const int m = (nm0 + r) % 9;
    const int l = (m >= 4) ? 2 : (m >= 1 ? 1 : 0);
    const float4* xv = (const float4*)(xr + r * 64);
    const float4* wv = (const float4*)(w + l * 4096 + d * 64);
    float acc = (m == 0) ? bias[d] : 0.f;
    #pragma unroll
    for (int q = 0; q < 16; ++q) {
        float4 a = xv[q], b = wv[q];
        acc += a.x * b.x + a.y * b.y + a.z * b.z + a.w * b.w;
    }
    y[nm0 * 64 + t] = acc;
}

// ---- K3: core tensor product. 1 atom/block, 6 waves = (mt, ng) ----
__global__ __launch_bounds__(384, 6) void mace_core(
    const float* __restrict__ xvg,          // [1024][9][64] (= d_out temp)
    const int*   __restrict__ anum,
    const float* __restrict__ W3,           // [E][16][64]
    const float* __restrict__ W2,           // [E][4][64]
    const float* __restrict__ U1,           // [9][9][2]
    const float* __restrict__ W1,           // [E][2][64]
    const _Float16* __restrict__ U3w,       // packed B-frags
    float* __restrict__ o1g)                // [1024][9][64] (ws)
{
    __shared__ float xvL[576];
    __shared__ __align__(16) float o2L[96 * 68];

    const int n  = blockIdx.x;
    const int t  = threadIdx.x;
    const int w  = t >> 6;          // 0..5
    const int l  = t & 63;
    const int mt = w & 1, ng = w >> 1;
    const int c32 = l & 31, hf = l >> 5;
    const int c  = mt * 32 + c32;   // this wave's channel

    for (int i = t; i < 576; i += 384) xvL[i] = xvg[n * 576 + i];
    __syncthreads();

    const int an = anum[n];
    const float* W3r = W3 + an * 1024;
    const float* W2r = W2 + an * 256;

    // A-frags in regs: s3f[i][j] = x_i(c) * w3_p(c), p = hf*8+j
    f16x8 s3f[9];
    {
        f16x8 w3h;
        #pragma unroll
        for (int j = 0; j < 8; ++j)
            w3h[j] = (_Float16)W3r[(hf * 8 + j) * 64 + c];
        #pragma unroll
        for (int i = 0; i < 9; ++i) {
            _Float16 xi = (_Float16)xvL[i * 64 + c];
            f16x8 xi8 = {xi, xi, xi, xi, xi, xi, xi, xi};
            s3f[i] = w3h * xi8;
        }
    }

    f32x16 acc = {0.f};
    const f16x8* Bp = (const f16x8*)U3w + ng * 64 + l;
    for (int b = 0; b < 9; ++b) {
        _Float16 h = (_Float16)xvL[b * 64 + c];
        f16x8 xb = {h, h, h, h, h, h, h, h};
        const f16x8* Bb = Bp + b * 9 * 192;
        #pragma unroll
        for (int ksub = 0; ksub < 9; ++ksub)
            acc = __builtin_amdgcn_mfma_f32_32x32x16_f16(s3f[ksub] * xb, Bb[ksub * 192], acc, 0, 0, 0);
    }
    // U2 tail: 3 k-steps (B pre-packed/zero-padded; A guarded)
    #pragma unroll
    for (int ks2 = 0; ks2 < 3; ++ks2) {
        f16x8 a;
        #pragma unroll
        for (int j = 0; j < 8; ++j) {
            int ip2 = ks2 * 16 + hf * 8 + j;
            int ii = ip2 >> 2, pp = ip2 & 3;
            float f = (ii < 9) ? xvL[ii * 64 + c] * W2r[pp * 64 + c] : 0.f;
            a[j] = (_Float16)f;
        }
        acc = __builtin_amdgcn_mfma_f32_32x32x16_f16(a, Bp[(81 + ks2) * 192], acc, 0, 0, 0);
    }

    // D layout: col(oa) = lane&31, row(c-in-half) = (reg&3)+8*(reg>>2)+4*hf
    {
        const int oa = ng * 32 + c32;
        float* o2row = o2L + oa * 68 + mt * 32;
        #pragma unroll
        for (int q = 0; q < 4; ++q) {
            f32x4 v = {acc[q*4+0], acc[q*4+1], acc[q*4+2], acc[q*4+3]};
            *(f32x4*)(o2row + q * 8 + hf * 4) = v;
        }
    }
    __syncthreads();

    // out1[o,c] = sum_a o2[o*9+a][c]*x_a(c) + U1/W1 term
    #pragma unroll
    for (int it = 0; it < 2; ++it) {
        int idx = t + it * 384;
        if (idx < 576) {
            int o = idx >> 6, cc = idx & 63;
            float a1 = 0.f, sa = 0.f, sb = 0.f;
            #pragma unroll
            for (int a = 0; a < 9; ++a)
                a1 += o2L[(o * 9 + a) * 68 + cc] * xvL[a * 64 + cc];
            #pragma unroll
            for (int i2 = 0; i2 < 9; ++i2) {
                float xc = xvL[i2 * 64 + cc];
                sa += U1[o * 18 + i2 * 2]     * xc;
                sb += U1[o * 18 + i2 * 2 + 1] * xc;
            }
            o1g[n * 576 + idx] = a1 + sa * W1[an * 128 + cc] + sb * W1[an * 128 + 64 + cc];
        }
    }
}

extern "C" void kernel_launch(void* const* d_in, const int* in_sizes, int n_in,
                              void* d_out, int out_size, void* d_ws, size_t ws_size,
                              hipStream_t stream) {
    const float* irreps_x = (const float*)d_in[0];
    const int*   anum     = (const int*)d_in[1];
    const float* w_fc1    = (const float*)d_in[2];
    const float* b_fc1    = (const float*)d_in[3];
    const float* U3       = (const float*)d_in[4];
    const float* W3       = (const float*)d_in[5];
    const float* U2       = (const float*)d_in[6];
    const float* W2       = (const float*)d_in[7];
    const float* U1       = (const float*)d_in[8];
    const float* W1       = (const float*)d_in[9];
    const float* w_lin    = (const float*)d_in[10];
    const float* w_fc2    = (const float*)d_in[11];
    const float* b_fc2    = (const float*)d_in[12];
    float* out = (float*)d_out;

    // workspace layout: U3w 258048B | o1g 2359296B | wcomb 49152B (~2.67MB)
    _Float16* U3w  = (_Float16*)d_ws;
    float*    o1g  = (float*)((char*)d_ws + 258048);
    float*    wcomb= (float*)((char*)d_ws + 258048 + 2359296);
    float*    xvg  = out;   // d_out doubles as xv temp; fully rewritten by K4

    prep_misc<<<66, 256, 0, stream>>>(U3, U2, w_lin, w_fc2, U3w, wcomb);
    lin_k<<<2304, 256, 0, stream>>>(irreps_x, w_fc1, b_fc1, xvg);
    mace_core<<<1024, 384, 0, stream>>>(xvg, anum, W3, W2, U1, W1, U3w, o1g);
    lin_k<<<2304, 256, 0, stream>>>(o1g, wcomb, b_fc2, out);
}

// Round 8
// 168.200 us; speedup vs baseline: 1.0439x; 1.0439x over previous
//
#include <hip/hip_runtime.h>

// MACE body-3, round 8: 2 kernels.
//  K1 prep_misc : U3(+U2 tail) -> f16 B-frags (258KB, L2-resident)
//                 + wcomb[l] = w_fc2[l] @ w_lin[l] (fuses last two linears)
//  K2 mace_fused: per atom (1 atom/block, 6 waves, 1024 blocks, 4 blocks/CU):
//                 fc1 (VALU) -> s3 regs -> 84x MFMA 32x32x16 f16 GEMM
//                 -> out1 -> combined linear -> out.

typedef __attribute__((ext_vector_type(8)))  _Float16 f16x8;
typedef __attribute__((ext_vector_type(16))) float    f32x16;
typedef __attribute__((ext_vector_type(4)))  float    f32x4;

// ---- K1: U3/U2 fragment pack (blocks 0..62) + wcomb (blocks 63..65) ----
__global__ void prep_misc(const float* __restrict__ U3, const float* __restrict__ U2,
                          const float* __restrict__ w_lin, const float* __restrict__ w_fc2,
                          _Float16* __restrict__ U3w, float* __restrict__ wcomb)
{
    if (blockIdx.x < 63) {
        int idx = blockIdx.x * 256 + threadIdx.x;   // 63*256 = 16128 exactly
        int ks = idx / 192, r = idx % 192;
        int nt = r >> 6, l = r & 63;
        int oa = nt * 32 + (l & 31), half = l >> 5;
        f16x8 v;
        if (ks < 81) {
            int b = ks / 9, ksub = ks % 9, ip0 = ksub * 16 + half * 8;
            #pragma unroll
            for (int j = 0; j < 8; ++j) {
                float f = (oa < 81) ? U3[(oa * 9 + b) * 144 + ip0 + j] : 0.f;
                v[j] = (_Float16)f;
            }
        } else {
            int ip0 = (ks - 81) * 16 + half * 8;
            #pragma unroll
            for (int j = 0; j < 8; ++j) {
                int ip2 = ip0 + j;
                float f = (oa < 81 && ip2 < 36) ? U2[oa * 36 + ip2] : 0.f;
                v[j] = (_Float16)f;
            }
        }
        ((f16x8*)U3w)[idx] = v;
    } else {
        // wcomb[l][e][c] = sum_d w_fc2[l][e][d] * w_lin[l][d][c]
        int l = blockIdx.x - 63;
        const float* wf = w_fc2 + l * 4096;
        const float* wl = w_lin + l * 4096;
        for (int i = threadIdx.x; i < 4096; i += 256) {
            int e = i >> 6, c = i & 63;
            float s = 0.f;
            #pragma unroll 8
            for (int d = 0; d < 64; ++d) s += wf[e * 64 + d] * wl[d * 64 + c];
            wcomb[l * 4096 + i] = s;
        }
    }
}

// ---- K2: fully fused per-atom kernel ----
__global__ __launch_bounds__(384, 4) void mace_fused(
    const float* __restrict__ irreps_x,     // [1024][9][64]
    const int*   __restrict__ anum,
    const float* __restrict__ w_fc1,        // [3][64][64]
    const float* __restrict__ b_fc1,        // [64]
    const float* __restrict__ W3,           // [E][16][64]
    const float* __restrict__ W2,           // [E][4][64]
    const float* __restrict__ U1,           // [9][9][2]
    const float* __restrict__ W1,           // [E][2][64]
    const float* __restrict__ wcomb,        // [3][64][64]
    const float* __restrict__ b_fc2,        // [64]
    const _Float16* __restrict__ U3w,       // packed B-frags
    float* __restrict__ out)                // [1024][9][64]
{
    __shared__ float xinL[576];                 // input row; aliased as o1L later
    __shared__ float xvL[576];                  // fc1 output
    __shared__ __align__(16) float o2L[96 * 68];
    float* const o1L = xinL;                    // alias (input dead after fc1)

    const int n  = blockIdx.x;
    const int t  = threadIdx.x;
    const int w  = t >> 6;          // 0..5
    const int l  = t & 63;
    const int mt = w & 1, ng = w >> 1;
    const int c32 = l & 31, hf = l >> 5;
    const int c  = mt * 32 + c32;   // this wave's channel

    for (int i = t; i < 576; i += 384) xinL[i] = irreps_x[n * 576 + i];
    __syncthreads();

    // ---- fc1 (VALU): xvL[m][d] = (m==0)b + sum_c xin[m][c] w_fc1[l][d][c]
    #pragma unroll
    for (int it = 0; it < 2; ++it) {
        int idx = t + it * 384;
        if (idx < 576) {
            int m = idx >> 6, d = idx & 63;
            int lm = (m >= 4) ? 2 : (m >= 1 ? 1 : 0);
            const float4* xr = (const float4*)(xinL + m * 64);
            const float4* wr = (const float4*)(w_fc1 + lm * 4096 + d * 64);
            float a = (m == 0) ? b_fc1[d] : 0.f;
            #pragma unroll
            for (int q = 0; q < 16; ++q) {
                float4 x4 = xr[q], w4 = wr[q];
                a += x4.x * w4.x + x4.y * w4.y + x4.z * w4.z + x4.w * w4.w;
            }
            xvL[idx] = a;
        }
    }
    __syncthreads();

    const int an = anum[n];
    const float* W3r = W3 + an * 1024;
    const float* W2r = W2 + an * 256;

    // ---- A-frags in regs: s3f[i][j] = x_i(c) * w3_{hf*8+j}(c)
    f16x8 s3f[9];
    {
        f16x8 w3h;
        #pragma unroll
        for (int j = 0; j < 8; ++j)
            w3h[j] = (_Float16)W3r[(hf * 8 + j) * 64 + c];
        #pragma unroll
        for (int i = 0; i < 9; ++i) {
            _Float16 xi = (_Float16)xvL[i * 64 + c];
            f16x8 xi8 = {xi, xi, xi, xi, xi, xi, xi, xi};
            s3f[i] = w3h * xi8;
        }
    }

    // ---- main GEMM: 84 MFMA (81 U3 + 3 U2 tail)
    f32x16 acc = {0.f};
    const f16x8* Bp = (const f16x8*)U3w + ng * 64 + l;
    for (int b = 0; b < 9; ++b) {
        _Float16 h = (_Float16)xvL[b * 64 + c];
        f16x8 xb = {h, h, h, h, h, h, h, h};
        const f16x8* Bb = Bp + b * 9 * 192;
        #pragma unroll
        for (int ksub = 0; ksub < 9; ++ksub)
            acc = __builtin_amdgcn_mfma_f32_32x32x16_f16(s3f[ksub] * xb, Bb[ksub * 192], acc, 0, 0, 0);
    }
    #pragma unroll
    for (int ks2 = 0; ks2 < 3; ++ks2) {
        f16x8 a;
        #pragma unroll
        for (int j = 0; j < 8; ++j) {
            int ip2 = ks2 * 16 + hf * 8 + j;
            int ii = ip2 >> 2, pp = ip2 & 3;
            float f = (ii < 9) ? xvL[ii * 64 + c] * W2r[pp * 64 + c] : 0.f;
            a[j] = (_Float16)f;
        }
        acc = __builtin_amdgcn_mfma_f32_32x32x16_f16(a, Bp[(81 + ks2) * 192], acc, 0, 0, 0);
    }

    // ---- store o2 (D: col oa = l&31, row = (reg&3)+8*(reg>>2)+4*hf)
    {
        const int oa = ng * 32 + c32;
        float* o2row = o2L + oa * 68 + mt * 32;
        #pragma unroll
        for (int q = 0; q < 4; ++q) {
            f32x4 v = {acc[q*4+0], acc[q*4+1], acc[q*4+2], acc[q*4+3]};
            *(f32x4*)(o2row + q * 8 + hf * 4) = v;
        }
    }
    __syncthreads();

    // ---- out1[o,c] = sum_a o2[o*9+a][c]*x_a(c) + U1/W1 term -> o1L (alias xinL)
    #pragma unroll
    for (int it = 0; it < 2; ++it) {
        int idx = t + it * 384;
        if (idx < 576) {
            int o = idx >> 6, cc = idx & 63;
            float a1 = 0.f, sa = 0.f, sb = 0.f;
            #pragma unroll
            for (int a = 0; a < 9; ++a)
                a1 += o2L[(o * 9 + a) * 68 + cc] * xvL[a * 64 + cc];
            #pragma unroll
            for (int i2 = 0; i2 < 9; ++i2) {
                float xc = xvL[i2 * 64 + cc];
                sa += U1[o * 18 + i2 * 2]     * xc;
                sb += U1[o * 18 + i2 * 2 + 1] * xc;
            }
            o1L[idx] = a1 + sa * W1[an * 128 + cc] + sb * W1[an * 128 + 64 + cc];
        }
    }
    __syncthreads();

    // ---- combined linear: out[m][d] = (m==0)b_fc2[d] + sum_c wcomb[l][d][c] o1[m][c]
    #pragma unroll
    for (int it = 0; it < 2; ++it) {
        int idx = t + it * 384;
        if (idx < 576) {
            int m = idx >> 6, d = idx & 63;
            int lm = (m >= 4) ? 2 : (m >= 1 ? 1 : 0);
            const float4* xr = (const float4*)(o1L + m * 64);
            const float4* wr = (const float4*)(wcomb + lm * 4096 + d * 64);
            float a = (m == 0) ? b_fc2[d] : 0.f;
            #pragma unroll
            for (int q = 0; q < 16; ++q) {
                float4 x4 = xr[q], w4 = wr[q];
                a += x4.x * w4.x + x4.y * w4.y + x4.z * w4.z + x4.w * w4.w;
            }
            out[n * 576 + idx] = a;
        }
    }
}

extern "C" void kernel_launch(void* const* d_in, const int* in_sizes, int n_in,
                              void* d_out, int out_size, void* d_ws, size_t ws_size,
                              hipStream_t stream) {
    const float* irreps_x = (const float*)d_in[0];
    const int*   anum     = (const int*)d_in[1];
    const float* w_fc1    = (const float*)d_in[2];
    const float* b_fc1    = (const float*)d_in[3];
    const float* U3       = (const float*)d_in[4];
    const float* W3       = (const float*)d_in[5];
    const float* U2       = (const float*)d_in[6];
    const float* W2       = (const float*)d_in[7];
    const float* U1       = (const float*)d_in[8];
    const float* W1       = (const float*)d_in[9];
    const float* w_lin    = (const float*)d_in[10];
    const float* w_fc2    = (const float*)d_in[11];
    const float* b_fc2    = (const float*)d_in[12];
    float* out = (float*)d_out;

    // workspace: U3w 258048B | wcomb 49152B
    _Float16* U3w   = (_Float16*)d_ws;
    float*    wcomb = (float*)((char*)d_ws + 258048);

    prep_misc<<<66, 256, 0, stream>>>(U3, U2, w_lin, w_fc2, U3w, wcomb);
    mace_fused<<<1024, 384, 0, stream>>>(irreps_x, anum, w_fc1, b_fc1, W3, W2,
                                         U1, W1, wcomb, b_fc2, U3w, out);
}